// Round 15
// baseline (4852.508 us; speedup 1.0000x reference)
//
#include <hip/hip_runtime.h>

#define T_STEPS 1000
#define NIN     128
#define NREC    512
#define NBATCH  64
#define ALPHA   0.2f

typedef _Float16 f16x8 __attribute__((ext_vector_type(8)));
typedef float    f32x4 __attribute__((ext_vector_type(4)));

// d_ws layout: [0, 512KB) = Wt fp16 (512x512, TRANSPOSED: Wt[j][k] = W_eff[k][j])
// (fallback fp32 W_eff occupies [0, 1MB) if the fp16 path is disabled)
#define WS_WT_BYTES (NREC * NREC * 2)

// lgkm-only barrier (proven r6-r14): drains LDS ops, NOT vmcnt, so the
// update phase's io stores and next-row prefetch loads stay in flight.
#define LDS_BARRIER() do {                                        \
    asm volatile("s_waitcnt lgkmcnt(0)" ::: "memory");            \
    __builtin_amdgcn_s_barrier();                                 \
    asm volatile("" ::: "memory");                                \
} while (0)

// ---------------------------------------------------------------------------
// Wt[j][k] = (fp16)( ei[k] * w_rec[k][j] * autapse[k][j] )   (transposed so
// the k-direction is contiguous: fragment fills become single b128 loads)
// ---------------------------------------------------------------------------
__global__ void weff_f16_kernel(const float* __restrict__ w_rec,
                                const float* __restrict__ ei_mask,
                                const float* __restrict__ autapse,
                                _Float16* __restrict__ wt) {
    int idx = blockIdx.x * blockDim.x + threadIdx.x;   // idx = j*512 + k
    if (idx < NREC * NREC) {
        int j = idx >> 9;
        int k = idx & (NREC - 1);
        float v = ei_mask[k * NREC + k] * w_rec[k * NREC + j]
                  * autapse[k * NREC + j];
        wt[idx] = (_Float16)v;
    }
}

// fp32 W_eff for the fallback path
__global__ void weff_kernel(const float* __restrict__ w_rec,
                            const float* __restrict__ ei_mask,
                            const float* __restrict__ autapse,
                            float* __restrict__ w_eff) {
    int idx = blockIdx.x * blockDim.x + threadIdx.x;
    if (idx < NREC * NREC) {
        int row = idx >> 9;
        float ei = ei_mask[row * NREC + row];
        w_eff[idx] = ei * w_rec[idx] * autapse[idx];
    }
}

// ---------------------------------------------------------------------------
// inp_all[m][j] = sum_k x[m][k] * w_in[k][j] + b_rec[j]   (into d_out)
// ---------------------------------------------------------------------------
__global__ __launch_bounds__(1024) void gemm_in_kernel(
        const float* __restrict__ x,
        const float* __restrict__ w_in,
        const float* __restrict__ b_rec,
        float* __restrict__ io) {
    __shared__ float xs[32][NIN];

    const int tid = threadIdx.x;
    const int m0  = blockIdx.x * 32;

    {
        const float4* src = reinterpret_cast<const float4*>(x + (size_t)m0 * NIN);
        reinterpret_cast<float4*>(&xs[0][0])[tid] = src[tid];
    }
    __syncthreads();

    const int j0 = tid & 255;
    const int j1 = j0 + 256;
    const int rg = tid >> 8;

    float acc[8][2];
#pragma unroll
    for (int i = 0; i < 8; ++i) { acc[i][0] = 0.f; acc[i][1] = 0.f; }

#pragma unroll 4
    for (int k = 0; k < NIN; ++k) {
        float wv0 = w_in[k * NREC + j0];
        float wv1 = w_in[k * NREC + j1];
#pragma unroll
        for (int i = 0; i < 8; ++i) {
            float xv = xs[rg * 8 + i][k];
            acc[i][0] = fmaf(xv, wv0, acc[i][0]);
            acc[i][1] = fmaf(xv, wv1, acc[i][1]);
        }
    }

    const float br0 = b_rec[j0];
    const float br1 = b_rec[j1];
#pragma unroll
    for (int i = 0; i < 8; ++i) {
        size_t ro = (size_t)(m0 + rg * 8 + i) * NREC;
        io[ro + j0] = acc[i][0] + br0;
        io[ro + j1] = acc[i][1] + br1;
    }
}

// ---------------------------------------------------------------------------
// Recurrence: ONE block per batch, NO inter-block communication.
// 512 threads = 8 waves. Wave w: kh = w>>2 (K-half of 256), ng = w&3
// (N-slice of 128 cols). Full W_eff lives in this block's registers as
// fp16 MFMA B-fragments: wf[kt][nt] (8x8 f16x8 = 256 VGPRs/lane).
//   B-frag (16x16x32): lane l holds B[8*(l>>4)+j][l&15], j=0..7
//   A-frag:            lane l holds A[l&15][8*(l>>4)+j]  -> row 0 = h,
//                      rows 1-15 zeroed (M=1 GEMV; waste is free on MFMA)
//   C/D   (m89):       col = lane&15, row = (lane>>4)*4 + reg -> row 0 is
//                      lanes 0-15, reg 0
// Per step: build 8 A-frags from packed-fp16 h in LDS (8 ds_read_b128),
// 64 MFMA (8 kt x 8 nt), extract row 0 -> part[kh][col], lgkm barrier,
// 512 update threads (fp32 state; h quantized to fp16 ONLY as MFMA input),
// write h to LDS, store io row, prefetch next row, lgkm barrier.
// ---------------------------------------------------------------------------
__global__ __launch_bounds__(512, 1) void rnn_mfma(
        const _Float16* __restrict__ Wt,
        const float* __restrict__ noise,
        float* __restrict__ io) {
    __shared__ _Float16 hl[NREC];
    __shared__ float part[2][NREC];

    const int tid  = threadIdx.x;
    const int b    = blockIdx.x;
    const int w    = tid >> 6;
    const int ln   = tid & 63;
    const int lrow = ln & 15;
    const int lkb  = ln >> 4;              // k-block within fragment (0..3)
    const int kh   = w >> 2;               // K-half (0/1)
    const int ng   = w & 3;                // N-slice (0..3)

    // ---- one-time: load this wave's 64 W fragments (256 VGPRs) ----
    f16x8 wf[8][8];
#pragma unroll
    for (int kt = 0; kt < 8; ++kt)
#pragma unroll
        for (int nt = 0; nt < 8; ++nt) {
            const int col = ng * 128 + nt * 16 + lrow;
            const int kb  = kh * 256 + kt * 32 + lkb * 8;
            wf[kt][nt] = *reinterpret_cast<const f16x8*>(
                &Wt[(size_t)col * NREC + kb]);
        }

    hl[tid] = (_Float16)0.f;
    float hj = 0.f;
    const size_t iobase = (size_t)b * T_STEPS * NREC + tid;
    float inp = io[iobase];
    float nz  = noise[iobase];
    __syncthreads();

    for (int t = 0; t < T_STEPS; ++t) {
        // ---- A-fragments: row 0 = h slice, rows 1-15 = 0 ----
        f16x8 af[8];
#pragma unroll
        for (int kt = 0; kt < 8; ++kt) {
            f16x8 a;
#pragma unroll
            for (int j = 0; j < 8; ++j) a[j] = (_Float16)0.f;
            if (lrow == 0)
                a = *reinterpret_cast<const f16x8*>(
                    &hl[kh * 256 + kt * 32 + lkb * 8]);
            af[kt] = a;
        }

        // ---- 64 MFMA: C[0][col] = sum_k h[k] * W[k][col] ----
        f32x4 cc[8];
#pragma unroll
        for (int nt = 0; nt < 8; ++nt) {
            cc[nt][0] = 0.f; cc[nt][1] = 0.f;
            cc[nt][2] = 0.f; cc[nt][3] = 0.f;
        }
#pragma unroll
        for (int kt = 0; kt < 8; ++kt)
#pragma unroll
            for (int nt = 0; nt < 8; ++nt)
                cc[nt] = __builtin_amdgcn_mfma_f32_16x16x32_f16(
                    af[kt], wf[kt][nt], cc[nt], 0, 0, 0);

        // ---- extract row 0 (lanes 0-15, reg 0) into part[kh] ----
        if (ln < 16) {
#pragma unroll
            for (int nt = 0; nt < 8; ++nt)
                part[kh][ng * 128 + nt * 16 + ln] = cc[nt][0];
        }
        LDS_BARRIER();                     // B1: partials ready

        // ---- update: every thread owns one column ----
        {
            float pre  = part[0][tid] + part[1][tid] + inp + nz;
            float hnew = (1.f - ALPHA) * hj + ALPHA * fmaxf(pre, 0.f);
            hj = hnew;
            hl[tid] = (_Float16)hnew;      // fp16 ONLY as MFMA input
            io[iobase + (size_t)t * NREC] = hnew;
            if (t + 1 < T_STEPS) {         // prefetch next row (same-thread)
                inp = io[iobase + (size_t)(t + 1) * NREC];
                nz  = noise[iobase + (size_t)(t + 1) * NREC];
            }
        }
        LDS_BARRIER();                     // B2: hl ready for next A-build
    }
}

// ---------------------------------------------------------------------------
// Fallback (round-1 kernel, fp32) if ws_size is too small for Wt.
// ---------------------------------------------------------------------------
__global__ __launch_bounds__(1024) void rnn_kernel(
        const float* __restrict__ W,
        const float* __restrict__ noise,
        float* __restrict__ io) {
    __shared__ float h[NREC];
    __shared__ float part2[NREC];

    const int tid  = threadIdx.x;
    const int j    = tid & (NREC - 1);
    const int half = tid >> 9;
    const int b    = blockIdx.x;

    if (tid < NREC) h[tid] = 0.f;
    float hj = 0.f;
    __syncthreads();

    const int kb = half * 256;
    const float* wp = W + (size_t)kb * NREC + j;
    const size_t base = (size_t)b * T_STEPS * NREC + j;

    for (int t = 0; t < T_STEPS; ++t) {
        const size_t off = base + (size_t)t * NREC;
        float acc = (half == 0) ? (io[off] + noise[off]) : 0.f;
#pragma unroll
        for (int ku = 0; ku < 256; ku += 16) {
            float wv[16];
#pragma unroll
            for (int u = 0; u < 16; ++u) wv[u] = wp[(size_t)(ku + u) * NREC];
#pragma unroll
            for (int u = 0; u < 16; ++u) acc = fmaf(h[kb + ku + u], wv[u], acc);
        }
        if (half == 1) part2[j] = acc;
        __syncthreads();
        if (half == 0) {
            float pre  = acc + part2[j];
            float hnew = (1.f - ALPHA) * hj + ALPHA * fmaxf(pre, 0.f);
            io[off] = hnew;
            h[j] = hnew;
            hj = hnew;
        }
        __syncthreads();
    }
}

// ---------------------------------------------------------------------------
extern "C" void kernel_launch(void* const* d_in, const int* in_sizes, int n_in,
                              void* d_out, int out_size, void* d_ws, size_t ws_size,
                              hipStream_t stream) {
    const float* x       = (const float*)d_in[0];
    const float* w_in    = (const float*)d_in[1];
    const float* w_rec   = (const float*)d_in[2];
    const float* b_rec   = (const float*)d_in[3];
    const float* ei_mask = (const float*)d_in[4];
    const float* autapse = (const float*)d_in[5];
    const float* noise   = (const float*)d_in[6];
    float* out = (float*)d_out;

    gemm_in_kernel<<<dim3(64000 / 32), dim3(1024), 0, stream>>>(
        x, w_in, b_rec, out);

    if (ws_size >= (size_t)WS_WT_BYTES) {
        _Float16* Wt = (_Float16*)d_ws;
        weff_f16_kernel<<<dim3((NREC * NREC + 255) / 256), dim3(256),
                          0, stream>>>(w_rec, ei_mask, autapse, Wt);
        rnn_mfma<<<dim3(NBATCH), dim3(512), 0, stream>>>(Wt, noise, out);
    } else {
        float* W = (float*)d_ws;
        weff_kernel<<<dim3((NREC * NREC + 255) / 256), dim3(256),
                      0, stream>>>(w_rec, ei_mask, autapse, W);
        rnn_kernel<<<dim3(NBATCH), dim3(1024), 0, stream>>>(W, noise, out);
    }
}